// Round 6
// baseline (498.136 us; speedup 1.0000x reference)
//
#include <hip/hip_runtime.h>
#include <hip/hip_fp16.h>

// Stacked GRU (T=50, B=1, H=256) on MI355X — round 6.
// Round-4 structure (agent-scope tagged atomics = correctness anchor) plus a
// DUAL-PATH fast exchange: producers additionally publish via
// global_atomic_swap_x2 (commits at the local XCD L2); consumers poll via
// returning global_atomic_add_x2(+0) sc0 (atomic load AT the L2, never L1).
// Scan blocks elect themselves onto one XCD (XCC_ID pigeonhole). If the fast
// path is not visible (wrong placement / semantics), each block latches
// fast_ok=false after a bounded probe and runs the proven slow path.

#define T_STEPS 50
#define VIN 768
#define VF 128
#define MIN_ 2
#define H 256
#define G3 768

#define NB 32
#define BT 256
#define HJ 8
#define ROWS 24
#define WSLICE (4*ROWS*256)
#define BAIL 4000000
#define NBLOCKS 264

typedef unsigned long long u64;

__device__ __forceinline__ float sigm(float x){ return 1.0f/(1.0f+expf(-x)); }
__device__ __forceinline__ float eluf(float x){ return x > 0.0f ? x : expm1f(x); }

__device__ __forceinline__ u64 ald(const u64* p){
  return __hip_atomic_load(const_cast<u64*>(p), __ATOMIC_RELAXED, __HIP_MEMORY_SCOPE_AGENT);
}
__device__ __forceinline__ void ast(u64* p, u64 v){
  __hip_atomic_store(p, v, __ATOMIC_RELAXED, __HIP_MEMORY_SCOPE_AGENT);
}
__device__ __forceinline__ u64 packtv(unsigned tag, float v){
  union{ float f; unsigned u; } c; c.f = v;
  return ((u64)tag << 32) | (u64)c.u;
}
__device__ __forceinline__ float unpackv(u64 x){
  union{ unsigned u; float f; } c; c.u = (unsigned)x; return c.f;
}

// fast poll: atomic add-0 (returning) at L2 scope; whole-wave success latch.
__device__ __forceinline__ bool poll_fast(u64* base, int lane, unsigned tag, float* h, int tries){
  u64* p = base + lane;
  u64 zero = 0;
  for (int i = 0; i < tries; ++i){
    u64 x0, x1, x2, x3;
    asm volatile(
      "global_atomic_add_x2 %0, %4, %8, off sc0\n\t"
      "global_atomic_add_x2 %1, %5, %8, off sc0\n\t"
      "global_atomic_add_x2 %2, %6, %8, off sc0\n\t"
      "global_atomic_add_x2 %3, %7, %8, off sc0\n\t"
      "s_waitcnt vmcnt(0)"
      : "=&v"(x0), "=&v"(x1), "=&v"(x2), "=&v"(x3)
      : "v"(p), "v"(p+64), "v"(p+128), "v"(p+192), "v"(zero)
      : "memory");
    bool ok = (((unsigned)(x0>>32))==tag) & (((unsigned)(x1>>32))==tag)
            & (((unsigned)(x2>>32))==tag) & (((unsigned)(x3>>32))==tag);
    if (__all(ok)){
      h[      lane] = unpackv(x0);
      h[ 64 + lane] = unpackv(x1);
      h[128 + lane] = unpackv(x2);
      h[192 + lane] = unpackv(x3);
      return true;
    }
  }
  return false;
}

// slow poll: agent-scope grouped loads (round-4 proven path).
__device__ __forceinline__ void poll_slow(const u64* base, int lane, unsigned tag, float* h){
  const u64* p = base + lane;
  int guard = 0;
  while (true){
    u64 x0 = ald(p), x1 = ald(p+64), x2 = ald(p+128), x3 = ald(p+192);
    bool ok = (((unsigned)(x0>>32))==tag) & (((unsigned)(x1>>32))==tag)
            & (((unsigned)(x2>>32))==tag) & (((unsigned)(x3>>32))==tag);
    if (ok | (++guard > BAIL)){
      h[      lane] = unpackv(x0);
      h[ 64 + lane] = unpackv(x1);
      h[128 + lane] = unpackv(x2);
      h[192 + lane] = unpackv(x3);
      break;
    }
    if (guard > 2000) __builtin_amdgcn_s_sleep(1);
  }
}

// nrows row-dots of one 24x256 f16 slice; lane's 4 swizzled cols are
// {lane, 64+lane, 128+lane, 192+lane}; lane0 writes out[lr].
__device__ __forceinline__ void dot_rows(const __half* wm, float a0, float a1, float a2, float a3,
                                         float* out, int base_lr, int nrows, int lane){
  #pragma unroll
  for (int rr = 0; rr < nrows; ++rr){
    const int lr = base_lr + rr;
    const __half2* w = reinterpret_cast<const __half2*>(wm + (lr << 8));
    float2 f0 = __half22float2(w[2*lane]);
    float2 f1 = __half22float2(w[2*lane+1]);
    float s = f0.x*a0 + f0.y*a1 + f1.x*a2 + f1.y*a3;
    #pragma unroll
    for (int off = 32; off; off >>= 1) s += __shfl_xor(s, off);
    if (lane == 0) out[lr] = s;
  }
}

__global__ __launch_bounds__(BT) void fused_kernel(
    const float* __restrict__ v0, const float* __restrict__ m0,
    const float* __restrict__ W1v, const float* __restrict__ b1v,
    const float* __restrict__ W1m, const float* __restrict__ b1m,
    const float* __restrict__ Wih_low, const float* __restrict__ Whh_low,
    const float* __restrict__ bih_low, const float* __restrict__ bhh_low,
    const float* __restrict__ Wih_high, const float* __restrict__ Whh_high,
    const float* __restrict__ bih_high, const float* __restrict__ bhh_high,
    const float* __restrict__ W2v, const float* __restrict__ b2v,
    const float* __restrict__ W2m, const float* __restrict__ b2m,
    float* __restrict__ out,
    u64* h1xf, u64* h2xf, u64* h1xs, u64* h2xs,
    u64* gxt, u64* h1ot, unsigned* ectl)
{
  __shared__ __half w_lds[WSLICE];
  __shared__ float h1n[H], h2n[H];
  __shared__ float gA[2*ROWS], gB[2*ROWS];
  __shared__ float xbuf[H];
  __shared__ int s_role, s_idx;

  const int tid = threadIdx.x;
  const int wv = tid >> 6, lane = tid & 63;

  // ---------------- election: find one XCD with >=32 blocks (pigeonhole) ----
  if (tid == 0){
    unsigned xcd;
    asm volatile("s_getreg_b32 %0, hwreg(HW_REG_XCC_ID, 0, 32)" : "=s"(xcd));
    xcd &= 7u;
    unsigned tk = atomicAdd(&ectl[xcd], 1u);
    if (tk == 31u) atomicCAS(&ectl[8], 0u, xcd + 1u);
    unsigned ch; int guard = 0;
    while (!(ch = __hip_atomic_load(&ectl[8], __ATOMIC_RELAXED, __HIP_MEMORY_SCOPE_AGENT))){
      __builtin_amdgcn_s_sleep(2);
      if (++guard > BAIL){ ch = 1u; break; }
    }
    if (xcd == ch - 1u && tk < 32u){ s_role = 0; s_idx = (int)tk; }
    else {
      unsigned ak = atomicAdd(&ectl[9], 1u);
      if      (ak < 50u ){ s_role = 1; s_idx = (int)ak; }
      else if (ak < 100u){ s_role = 2; s_idx = (int)(ak - 50u); }
      else               { s_role = 3; s_idx = 0; }
    }
  }
  __syncthreads();
  const int role = s_role, idx = s_idx;
  if (role == 3) return;

  if (role == 0){
    // ================================================== scan role
    const int b = idx;
    for (int i = tid; i < WSLICE; i += BT){
      int c_sw = i & 255;
      int r2 = i >> 8;
      int lr = r2 % ROWS, m = r2 / ROWS;
      int c = (c_sw & 3)*64 + (c_sw >> 2);
      int g = lr / HJ, j = lr % HJ;
      int row = g*H + b*HJ + j;
      float v;
      if      (m == 0) v = Wih_low [row*(2*H) + H + c];
      else if (m == 1) v = Whh_low [row*H + c];
      else if (m == 2) v = Wih_high[row*H + c];
      else             v = Whh_high[row*H + c];
      w_lds[i] = __float2half(v);
    }
    if (tid < H) h2n[tid] = 0.f;
    if (tid < 2*ROWS) gA[tid] = 0.f;
    __syncthreads();

    const __half* w_m0 = w_lds;               // Wih_low[:,256:512] (gi_A)
    const __half* w_m1 = w_lds + 1*ROWS*256;  // Whh_low   (gh_A)
    const __half* w_m2 = w_lds + 2*ROWS*256;  // Wih_high  (gi_B)
    const __half* w_m3 = w_lds + 3*ROWS*256;  // Whh_high  (gh_B)

    float hv1 = 0.f, hv2 = 0.f;
    float blR=0,blZ=0,blN=0, biR=0,biZ=0,biN=0, bhR=0,bhZ=0,bhN=0;
    float gxR=0, gxZ=0, gxN=0;
    bool fast_ok = true;                      // latched by wave0 polls
    const int jg = b*HJ + lane;               // valid for wv==0 && lane<HJ
    if (wv == 0 && lane < HJ){
      blR = bhh_low [jg]; blZ = bhh_low [H+jg]; blN = bhh_low [2*H+jg];
      biR = bih_high[jg]; biZ = bih_high[H+jg]; biN = bih_high[2*H+jg];
      bhR = bhh_high[jg]; bhZ = bhh_high[H+jg]; bhN = bhh_high[2*H+jg];
      const u64* g = gxt + jg;                // initial Gx[0] poll (agent)
      int guard = 0;
      while (true){
        u64 a0 = ald(g), a1 = ald(g + H), a2 = ald(g + 2*H);
        bool ok = (((unsigned)(a0>>32))==1u) & (((unsigned)(a1>>32))==1u) & (((unsigned)(a2>>32))==1u);
        if (ok | (++guard > BAIL)){ gxR=unpackv(a0); gxZ=unpackv(a1); gxN=unpackv(a2); break; }
        __builtin_amdgcn_s_sleep(4);
      }
    }

    for (int t = 0; t < T_STEPS; ++t){
      const int par = t & 1;
      const unsigned tag = (unsigned)(t + 1);

      // ---- segment 1: A finalize + dual fanout (wave0) | gh_B (waves 1-3)
      if (wv == 0){
        if (lane < HJ){
          float giR = gA[lane]      + gxR, ghR = gA[ROWS+lane]      + blR;
          float giZ = gA[HJ+lane]   + gxZ, ghZ = gA[ROWS+HJ+lane]   + blZ;
          float giN = gA[2*HJ+lane] + gxN, ghN = gA[ROWS+2*HJ+lane] + blN;
          float r = sigm(giR + ghR), z = sigm(giZ + ghZ);
          float n = tanhf(giN + r * ghN);
          hv1 = (1.f - z) * n + z * hv1;
          u64 pk = packtv(tag, hv1);
          u64* df = h1xf + (par<<8) + (b<<3) + lane;
          #pragma unroll
          for (int c = 0; c < NB; ++c)
            asm volatile("global_atomic_swap_x2 %0, %1, off" :: "v"(df + (c<<9)), "v"(pk) : "memory");
          u64* ds = h1xs + (par<<8) + (b<<3) + lane;
          #pragma unroll
          for (int c = 0; c < NB; ++c) ast(ds + (c<<9), pk);
          ast(h1ot + (size_t)t*H + jg, packtv(1u, hv1));   // cross-XCD to post
        }
      } else {
        float a0=h2n[lane], a1=h2n[64+lane], a2=h2n[128+lane], a3=h2n[192+lane];
        dot_rows(w_m3, a0,a1,a2,a3, gB + ROWS, (wv-1)*8, 8, lane);   // gh_B
      }
      if (t == T_STEPS - 1) break;
      if (wv == 0){
        bool got = false;
        if (fast_ok){
          got = poll_fast(h1xf + (b<<9) + (par<<8), lane, tag, h1n, t==0 ? 20000 : 200000);
          fast_ok = got;
        }
        if (!got) poll_slow(h1xs + (b<<9) + (par<<8), lane, tag, h1n);
      }
      __syncthreads();                                   // sync1: h1n + gh_B ready

      // ---- segment 2: gi_B (waves 1-3) | Gx[t+1] prefetch (wave0, agent)
      if (wv == 0){
        if (lane < HJ){
          const u64* g = gxt + (size_t)(t+1)*G3 + jg;
          int guard = 0;
          while (true){
            u64 a0 = ald(g), a1 = ald(g + H), a2 = ald(g + 2*H);
            bool ok = (((unsigned)(a0>>32))==1u) & (((unsigned)(a1>>32))==1u) & (((unsigned)(a2>>32))==1u);
            if (ok | (++guard > BAIL)){ gxR=unpackv(a0); gxZ=unpackv(a1); gxN=unpackv(a2); break; }
            __builtin_amdgcn_s_sleep(2);
          }
        }
      } else {
        float a0=h1n[lane], a1=h1n[64+lane], a2=h1n[128+lane], a3=h1n[192+lane];
        dot_rows(w_m2, a0,a1,a2,a3, gB, (wv-1)*8, 8, lane);          // gi_B
      }
      __syncthreads();                                   // sync2: gB complete

      // ---- segment 3: B finalize + dual fanout (wave0) | gh_A' (waves 1-3)
      if (wv == 0){
        if (lane < HJ){
          float giR = gB[lane]      + biR, ghR = gB[ROWS+lane]      + bhR;
          float giZ = gB[HJ+lane]   + biZ, ghZ = gB[ROWS+HJ+lane]   + bhZ;
          float giN = gB[2*HJ+lane] + biN, ghN = gB[ROWS+2*HJ+lane] + bhN;
          float r = sigm(giR + ghR), z = sigm(giZ + ghZ);
          float n = tanhf(giN + r * ghN);
          hv2 = (1.f - z) * n + z * hv2;
          u64 pk = packtv(tag, hv2);
          u64* df = h2xf + (par<<8) + (b<<3) + lane;
          #pragma unroll
          for (int c = 0; c < NB; ++c)
            asm volatile("global_atomic_swap_x2 %0, %1, off" :: "v"(df + (c<<9)), "v"(pk) : "memory");
          u64* ds = h2xs + (par<<8) + (b<<3) + lane;
          #pragma unroll
          for (int c = 0; c < NB; ++c) ast(ds + (c<<9), pk);
        }
      } else {
        float a0=h1n[lane], a1=h1n[64+lane], a2=h1n[128+lane], a3=h1n[192+lane];
        dot_rows(w_m1, a0,a1,a2,a3, gA + ROWS, (wv-1)*8, 8, lane);   // gh_A'
      }
      if (wv == 0){
        bool got = false;
        if (fast_ok){
          got = poll_fast(h2xf + (b<<9) + (par<<8), lane, tag, h2n, 200000);
          fast_ok = got;
        }
        if (!got) poll_slow(h2xs + (b<<9) + (par<<8), lane, tag, h2n);
      }
      __syncthreads();                                   // sync3: h2n + gh_A' ready

      // ---- segment 4: gi_A' (all 4 waves, 6 rows each)
      { float a0=h2n[lane], a1=h2n[64+lane], a2=h2n[128+lane], a3=h2n[192+lane];
        dot_rows(w_m0, a0,a1,a2,a3, gA, wv*6, 6, lane); }            // gi_A'
      __syncthreads();                                   // sync4
    }

  } else if (role == 1){
    // ================================================== featgx role
    const int t = idx;
    { int j = tid >> 1, s = tid & 1;
      const float4* a4 = reinterpret_cast<const float4*>(v0 + (size_t)t*VIN) + s*96;
      const float4* w4 = reinterpret_cast<const float4*>(W1v + (size_t)j*VIN) + s*96;
      float p = 0.f;
      #pragma unroll 4
      for (int c = 0; c < 96; ++c){
        float4 a = a4[c], w = w4[c];
        p += a.x*w.x + a.y*w.y + a.z*w.z + a.w*w.w;
      }
      p += __shfl_xor(p, 1);
      if (s == 0) xbuf[j] = eluf(p + b1v[j]);
    }
    if (tid < VF){
      float am = b1m[tid] + W1m[tid*2]*m0[t*2] + W1m[tid*2+1]*m0[t*2+1];
      xbuf[VF + tid] = eluf(am);
    }
    __syncthreads();
    #pragma unroll
    for (int k = 0; k < 3; ++k){
      int r = k*256 + tid;
      const float4* w4 = reinterpret_cast<const float4*>(Wih_low + (size_t)r*(2*H));
      const float4* x4 = reinterpret_cast<const float4*>(xbuf);
      float acc = bih_low[r];
      #pragma unroll 8
      for (int c = 0; c < 64; ++c){
        float4 w = w4[c], x = x4[c];
        acc += w.x*x.x + w.y*x.y + w.z*x.z + w.w*x.w;
      }
      ast(gxt + (size_t)t*G3 + r, packtv(1u, acc));
    }

  } else {
    // ================================================== post role
    const int t = idx;
    for (int i = 0; i < t; ++i) __builtin_amdgcn_s_sleep(32);   // staggered start
    if (wv == 0){
      const u64* p = h1ot + (size_t)t*H + lane;
      int guard = 0;
      while (true){
        u64 x0 = ald(p), x1 = ald(p+64), x2 = ald(p+128), x3 = ald(p+192);
        bool ok = (((unsigned)(x0>>32))==1u) & (((unsigned)(x1>>32))==1u)
                & (((unsigned)(x2>>32))==1u) & (((unsigned)(x3>>32))==1u);
        if (ok | (++guard > BAIL)){
          xbuf[      lane] = eluf(unpackv(x0));
          xbuf[ 64 + lane] = eluf(unpackv(x1));
          xbuf[128 + lane] = eluf(unpackv(x2));
          xbuf[192 + lane] = eluf(unpackv(x3));
          break;
        }
        __builtin_amdgcn_s_sleep(8);
      }
    }
    __syncthreads();
    #pragma unroll
    for (int k = 0; k < 3; ++k){
      int r = k*256 + tid;
      const float4* w4 = reinterpret_cast<const float4*>(W2v + (size_t)r*VF);
      const float4* f4 = reinterpret_cast<const float4*>(xbuf);
      float acc = b2v[r];
      #pragma unroll 8
      for (int c = 0; c < 32; ++c){
        float4 w = w4[c], x = f4[c];
        acc += w.x*x.x + w.y*x.y + w.z*x.z + w.w*x.w;
      }
      out[(size_t)t*VIN + r] = sigm(acc);
    }
    if (tid < MIN_){
      const float* wm = W2m + tid*VF;
      float am = b2m[tid];
      #pragma unroll 8
      for (int c = 0; c < VF; ++c) am += wm[c] * xbuf[VF + c];
      out[(size_t)T_STEPS*VIN + t*MIN_ + tid] = tanhf(am);
    }
  }
}

extern "C" void kernel_launch(void* const* d_in, const int* in_sizes, int n_in,
                              void* d_out, int out_size, void* d_ws, size_t ws_size,
                              hipStream_t stream)
{
  const float* v0       = (const float*)d_in[0];
  const float* m0       = (const float*)d_in[1];
  const float* W1v      = (const float*)d_in[2];
  const float* b1v      = (const float*)d_in[3];
  const float* W1m      = (const float*)d_in[4];
  const float* b1m      = (const float*)d_in[5];
  const float* Wih_low  = (const float*)d_in[6];
  const float* Whh_low  = (const float*)d_in[7];
  const float* bih_low  = (const float*)d_in[8];
  const float* bhh_low  = (const float*)d_in[9];
  const float* Wih_high = (const float*)d_in[10];
  const float* Whh_high = (const float*)d_in[11];
  const float* bih_high = (const float*)d_in[12];
  const float* bhh_high = (const float*)d_in[13];
  const float* W2v      = (const float*)d_in[14];
  const float* b2v      = (const float*)d_in[15];
  const float* W2m      = (const float*)d_in[16];
  const float* b2m      = (const float*)d_in[17];
  float* out = (float*)d_out;

  // ws layout (8B-aligned). Poison 0xAA..AA != any tag used (1..50).
  // h1x*/h2x*: [copy c][par][256] u64 -> consumer b's region at (b<<9)+(par<<8).
  char* ws = (char*)d_ws;
  u64* h1xf     = (u64*)(ws + 0);               // 128 KB (fast, local-L2 atomics)
  u64* h2xf     = (u64*)(ws + 131072);          // 128 KB
  u64* h1xs     = (u64*)(ws + 262144);          // 128 KB (slow, agent scope)
  u64* h2xs     = (u64*)(ws + 393216);          // 128 KB
  u64* gxt      = (u64*)(ws + 524288);          // 300 KB
  u64* h1ot     = (u64*)(ws + 831488);          // 100 KB
  unsigned* ectl= (unsigned*)(ws + 933888);     // election counters

  hipMemsetAsync(ws + 933888, 0, 256, stream);  // zero election state only

  fused_kernel<<<NBLOCKS, BT, 0, stream>>>(
      v0, m0, W1v, b1v, W1m, b1m,
      Wih_low, Whh_low, bih_low, bhh_low,
      Wih_high, Whh_high, bih_high, bhh_high,
      W2v, b2v, W2m, b2m, out,
      h1xf, h2xf, h1xs, h2xs, gxt, h1ot, ectl);
}